// Round 1
// baseline (673.935 us; speedup 1.0000x reference)
//
#include <hip/hip_runtime.h>
#include <cstdint>

typedef unsigned short u16;
typedef __attribute__((ext_vector_type(8))) short s16x8;   // 8 bf16 (4 VGPRs)
typedef __attribute__((ext_vector_type(4))) float f32x4;

__device__ __forceinline__ u16 f2bf(float f) {
  unsigned int u = __float_as_uint(f);
  unsigned int r = u + 0x7FFFu + ((u >> 16) & 1u);   // RNE
  return (u16)(r >> 16);
}
__device__ __forceinline__ float bf2f(u16 b) {
  return __uint_as_float(((unsigned int)b) << 16);
}
__device__ __forceinline__ f32x4 mfma16(s16x8 a, s16x8 b, f32x4 c) {
  return __builtin_amdgcn_mfma_f32_16x16x32_bf16(a, b, c, 0, 0, 0);
}
__device__ __forceinline__ void gload16(const void* g, void* l) {
  __builtin_amdgcn_global_load_lds((const __attribute__((address_space(1))) void*)g,
                                   (__attribute__((address_space(3))) void*)l, 16, 0, 0);
}

// ---------- transpose + cast: in f32 [K][N] -> out bf16 [N][K] ----------
__global__ __launch_bounds__(256) void k_transpose_cast(const float* __restrict__ in,
                                                        u16* __restrict__ out,
                                                        int K, int N) {
  __shared__ float tile[32][33];
  int n0 = blockIdx.x * 32, k0 = blockIdx.y * 32;
  int tx = threadIdx.x & 31, ty = threadIdx.x >> 5;
#pragma unroll
  for (int i = 0; i < 32; i += 8)
    tile[ty + i][tx] = in[(size_t)(k0 + ty + i) * N + n0 + tx];
  __syncthreads();
#pragma unroll
  for (int i = 0; i < 32; i += 8)
    out[(size_t)(n0 + ty + i) * K + k0 + tx] = f2bf(tile[tx][ty + i]);
}

// ---------- masked mean + relu: grid (B, 4, 2) ----------
__global__ __launch_bounds__(256) void k_mean(const float* __restrict__ v,
                                              const float* __restrict__ q,
                                              const float* __restrict__ vm,
                                              const float* __restrict__ qm,
                                              float* __restrict__ rmean_v,
                                              float* __restrict__ rmean_q) {
  int b = blockIdx.x, dc = blockIdx.y, mod = blockIdx.z;
  const float* x  = mod ? q : v;
  const float* mk = mod ? qm : vm;
  float* out      = mod ? rmean_q : rmean_v;
  int d = dc * 256 + threadIdx.x;
  const float* xb = x + (size_t)b * 256 * 1024 + d;
  const float* mb = mk + b * 256;
  float s = 0.f, ms = 0.f;
  for (int n = 0; n < 256; ++n) {
    float m = mb[n];
    ms += m;
    s = fmaf(xb[(size_t)n * 1024], m, s);
  }
  float mean = s / ms;
  out[b * 1024 + d] = mean > 0.f ? mean : 0.f;
}

// ---------- gate: gs[b][d] = 1 + sigmoid(dot(rmean[b], W[:,d]) + bias[d]) ----------
__global__ __launch_bounds__(256) void k_gate(const float* __restrict__ rmean,
                                              const float* __restrict__ W,
                                              const float* __restrict__ bias,
                                              float* __restrict__ gs) {
  int b = blockIdx.y;
  int d = blockIdx.x * 256 + threadIdx.x;
  const float* r = rmean + b * 1024;
  float acc = bias[d];
#pragma unroll 8
  for (int k = 0; k < 1024; ++k) acc = fmaf(r[k], W[(size_t)k * 1024 + d], acc);
  gs[b * 1024 + d] = 1.f + 1.f / (1.f + expf(-acc));
}

// ---------- relu + bf16 cast: grid (4096,1,2), 8 elems/thread ----------
__global__ __launch_bounds__(256) void k_relucast(const float* __restrict__ v,
                                                  const float* __restrict__ q,
                                                  u16* __restrict__ ov,
                                                  u16* __restrict__ oq) {
  const float* x = blockIdx.z ? q : v;
  u16* o = blockIdx.z ? oq : ov;
  size_t i = (size_t)blockIdx.x * 256 + threadIdx.x;
  const f32x4* xv = (const f32x4*)x;
  f32x4 a = xv[2 * i], b = xv[2 * i + 1];
  s16x8 r;
#pragma unroll
  for (int j = 0; j < 4; ++j) r[j] = (short)f2bf(a[j] > 0.f ? a[j] : 0.f);
#pragma unroll
  for (int j = 0; j < 4; ++j) r[4 + j] = (short)f2bf(b[j] > 0.f ? b[j] : 0.f);
  ((s16x8*)o)[i] = r;
}

// ---------- MFMA GEMM: C[m][n] = A[m][:] . BT[n][:] + bias, 128x128 tile, BK=32 ----------
// EPI 0: trans epilogue (bf16 out, *mask(row), *gs for n<2048) ; EPI 1: f32 out
template <int EPI>
__global__ __launch_bounds__(256) void k_gemm(const u16* __restrict__ A,
                                              const u16* __restrict__ BT,
                                              const float* __restrict__ bias,
                                              u16* __restrict__ outb,
                                              float* __restrict__ outf,
                                              const float* __restrict__ mask,
                                              const float* __restrict__ gs,
                                              int K, int ldo) {
  __shared__ u16 lA[128 * 32];
  __shared__ u16 lB[128 * 32];
  int t = threadIdx.x;
  int w = t >> 6, lane = t & 63;
  int wr = w >> 1, wc = w & 1;
  int m0 = blockIdx.y * 128, n0 = blockIdx.x * 128;
  f32x4 acc[4][4] = {};

  int srow = lane >> 2;           // 0..15 within 16-row chunk
  int scol = (lane & 3) * 8;      // 0,8,16,24
  const u16* Abase = A + (size_t)m0 * K + scol;
  const u16* Bbase = BT + (size_t)n0 * K + scol;
  int la = lane & 15, lb = lane >> 4;

  for (int k0 = 0; k0 < K; k0 += 32) {
#pragma unroll
    for (int r = 0; r < 2; ++r) {
      int ch = r * 4 + w;                 // 0..7, wave-uniform
      int row = ch * 16 + srow;           // 0..127
      gload16(Abase + (size_t)row * K + k0, &lA[ch * 512]);
      gload16(Bbase + (size_t)row * K + k0, &lB[ch * 512]);
    }
    __syncthreads();
    s16x8 af[4], bfr[4];
#pragma unroll
    for (int i = 0; i < 4; ++i)
      af[i] = *(const s16x8*)&lA[(wr * 64 + i * 16 + la) * 32 + lb * 8];
#pragma unroll
    for (int i = 0; i < 4; ++i)
      bfr[i] = *(const s16x8*)&lB[(wc * 64 + i * 16 + la) * 32 + lb * 8];
#pragma unroll
    for (int i = 0; i < 4; ++i)
#pragma unroll
      for (int j = 0; j < 4; ++j)
        acc[i][j] = mfma16(af[i], bfr[j], acc[i][j]);
    __syncthreads();
  }

#pragma unroll
  for (int i = 0; i < 4; ++i) {
    int mbase = m0 + wr * 64 + i * 16 + lb * 4;
#pragma unroll
    for (int j = 0; j < 4; ++j) {
      int n = n0 + wc * 64 + j * 16 + la;
      float bn = bias[n];
#pragma unroll
      for (int r = 0; r < 4; ++r) {
        int m = mbase + r;
        float val = acc[i][j][r] + bn;
        if (EPI == 0) {
          int bidx = m >> 8;
          val *= mask[m];                              // mask flat [B*256]
          if (n < 2048) val *= gs[(bidx << 10) + (n & 1023)];
          outb[(size_t)m * 3072 + n] = f2bf(val);
        } else {
          outf[(size_t)m * ldo + n] = val;
        }
      }
    }
  }
}

// ---------- fused attention per (b, h, 64 q-rows): grid (64, 32) ----------
__global__ __launch_bounds__(256) void k_attn(const u16* __restrict__ trans,
                                              const float* __restrict__ mask,
                                              const float* __restrict__ xorig,
                                              u16* __restrict__ attin) {
  __shared__ u16 Vt[64 * 256];      // swizzled V^T [d][key], 32KB
  __shared__ u16 P[4 * 16 * 256];   // per-wave P [16][256], 32KB
  int h = blockIdx.x >> 2, qc = blockIdx.x & 3;
  int b = blockIdx.y;
  int t = threadIdx.x, w = t >> 6, lane = t & 63;
  const u16* tb = trans + (size_t)b * 256 * 3072;

  // stage V^T (v part = cols [2048, 3072)), XOR-swizzled rows of 512B
#pragma unroll
  for (int i = 0; i < 8; ++i) {
    int c = t + i * 256;
    int key = c >> 3, dc = c & 7;
    s16x8 vv = *(const s16x8*)(tb + (size_t)key * 3072 + 2048 + h * 64 + dc * 8);
    int quad = key >> 3, klow = key & 7;
#pragma unroll
    for (int j = 0; j < 8; ++j) {
      int d = dc * 8 + j;
      Vt[d * 256 + ((quad ^ (d & 7)) << 3) + klow] = (u16)vv[j];
    }
  }
  __syncthreads();

  int la = lane & 15, lb = lane >> 4;
  int q0 = qc * 64 + w * 16;
  const u16* qrow = tb + (size_t)(q0 + la) * 3072 + 1024 + h * 64;  // q part
  s16x8 qf0 = *(const s16x8*)(qrow + lb * 8);
  s16x8 qf1 = *(const s16x8*)(qrow + 32 + lb * 8);
  u16* Pw = &P[w * 4096];
  const float* mb = mask + b * 256;
  float rsum[4] = {0.f, 0.f, 0.f, 0.f};

  for (int nt = 0; nt < 16; ++nt) {
    const u16* kb = tb + (size_t)(nt * 16 + la) * 3072 + h * 64 + lb * 8;  // k part
    s16x8 kf0 = *(const s16x8*)kb;
    s16x8 kf1 = *(const s16x8*)(kb + 32);
    f32x4 s = {0.f, 0.f, 0.f, 0.f};
    s = mfma16(qf0, kf0, s);
    s = mfma16(qf1, kf1, s);
    int key = nt * 16 + la;
    float km = mb[key];
    int quad = key >> 3, klow = key & 7;
#pragma unroll
    for (int r = 0; r < 4; ++r) {
      float p = (km != 0.f) ? expf(s[r] * 0.125f) : 0.f;  // exp((masked?-1e9:s)/8)
      u16 pb = f2bf(p);
      int lr = lb * 4 + r;
      rsum[r] += bf2f(pb);
      Pw[lr * 256 + ((quad ^ (lr & 7)) << 3) + klow] = pb;
    }
  }
#pragma unroll
  for (int r = 0; r < 4; ++r) {
    rsum[r] += __shfl_xor(rsum[r], 1);
    rsum[r] += __shfl_xor(rsum[r], 2);
    rsum[r] += __shfl_xor(rsum[r], 4);
    rsum[r] += __shfl_xor(rsum[r], 8);
  }

  f32x4 o[4] = {};
  for (int kt = 0; kt < 8; ++kt) {
    int pq = kt * 4 + lb;
    s16x8 pa = *(const s16x8*)&Pw[la * 256 + ((pq ^ (la & 7)) << 3)];
#pragma unroll
    for (int dt = 0; dt < 4; ++dt) {
      int d = dt * 16 + la;
      s16x8 vb = *(const s16x8*)&Vt[d * 256 + ((pq ^ (d & 7)) << 3)];
      o[dt] = mfma16(pa, vb, o[dt]);
    }
  }

#pragma unroll
  for (int dt = 0; dt < 4; ++dt) {
    int dcol = h * 64 + dt * 16 + la;
#pragma unroll
    for (int r = 0; r < 4; ++r) {
      int qr = q0 + lb * 4 + r;
      size_t gi = ((size_t)b * 256 + qr) * 1024 + dcol;
      attin[gi] = f2bf(xorig[gi] + o[dt][r] / rsum[r]);
    }
  }
}

extern "C" void kernel_launch(void* const* d_in, const int* in_sizes, int n_in,
                              void* d_out, int out_size, void* d_ws, size_t ws_size,
                              hipStream_t stream) {
  const float* v      = (const float*)d_in[0];
  const float* q      = (const float*)d_in[1];
  const float* v_mask = (const float*)d_in[2];
  const float* q_mask = (const float*)d_in[3];
  const float* w_v4q  = (const float*)d_in[4];
  const float* b_v4q  = (const float*)d_in[5];
  const float* w_q4v  = (const float*)d_in[6];
  const float* b_q4v  = (const float*)d_in[7];
  const float* w_vlin = (const float*)d_in[8];
  const float* b_vlin = (const float*)d_in[9];
  const float* w_qlin = (const float*)d_in[10];
  const float* b_qlin = (const float*)d_in[11];
  const float* w_vout = (const float*)d_in[12];
  const float* b_vout = (const float*)d_in[13];
  const float* w_qout = (const float*)d_in[14];
  const float* b_qout = (const float*)d_in[15];
  float* out = (float*)d_out;

  char* ws = (char*)d_ws;
  u16* rbf_v     = (u16*)(ws);                    // 16.8MB, reused as attin_v
  u16* rbf_q     = (u16*)(ws + 16777216);         // 16.8MB, reused as attin_q
  u16* trans_v   = (u16*)(ws + 33554432);         // 50.3MB
  u16* wlinT_v   = (u16*)(ws + 83886080);         // 6.3MB
  u16* wlinT_q   = (u16*)(ws + 90177536);         // 6.3MB
  u16* woutT_v   = (u16*)(ws + 96468992);         // 2.1MB
  u16* woutT_q   = (u16*)(ws + 98566144);         // 2.1MB
  float* rmean_v = (float*)(ws + 100663296);
  float* rmean_q = (float*)(ws + 100794368);
  float* gs_v    = (float*)(ws + 100925440);      // 1+q4v_gate (gates v's q/k)
  float* gs_q    = (float*)(ws + 101056512);      // 1+v4q_gate (gates q's q/k)
  u16* trans_q   = (u16*)d_out;                   // 50.3MB parked in d_out; consumed
                                                  // by attn_q before gemm3 overwrites

  dim3 blk(256);
  // weights -> bf16 [N][K]
  k_transpose_cast<<<dim3(96, 32), blk, 0, stream>>>(w_vlin, wlinT_v, 1024, 3072);
  k_transpose_cast<<<dim3(96, 32), blk, 0, stream>>>(w_qlin, wlinT_q, 1024, 3072);
  k_transpose_cast<<<dim3(32, 32), blk, 0, stream>>>(w_vout, woutT_v, 1024, 1024);
  k_transpose_cast<<<dim3(32, 32), blk, 0, stream>>>(w_qout, woutT_q, 1024, 1024);
  // masked means (relu'd)
  k_mean<<<dim3(32, 4, 2), blk, 0, stream>>>(v, q, v_mask, q_mask, rmean_v, rmean_q);
  // gates (cross-wired: v-attention gated by q-mean and vice versa)
  k_gate<<<dim3(4, 32), blk, 0, stream>>>(rmean_q, w_q4v, b_q4v, gs_v);
  k_gate<<<dim3(4, 32), blk, 0, stream>>>(rmean_v, w_v4q, b_v4q, gs_q);
  // relu + cast
  k_relucast<<<dim3(4096, 1, 2), blk, 0, stream>>>(v, q, rbf_v, rbf_q);
  // trans = (relu(x) @ Wlin + b) * mask, k/q thirds * (1+gate)
  k_gemm<0><<<dim3(24, 64), blk, 0, stream>>>(rbf_v, wlinT_v, b_vlin, trans_v, nullptr,
                                              v_mask, gs_v, 1024, 0);
  k_gemm<0><<<dim3(24, 64), blk, 0, stream>>>(rbf_q, wlinT_q, b_qlin, trans_q, nullptr,
                                              q_mask, gs_q, 1024, 0);
  // attention; writes bf16(x + update) into rbf (attin)
  k_attn<<<dim3(64, 32), blk, 0, stream>>>(trans_v, v_mask, v, rbf_v);
  k_attn<<<dim3(64, 32), blk, 0, stream>>>(trans_q, q_mask, q, rbf_q);
  // out = attin @ Wout + b
  k_gemm<1><<<dim3(8, 64), blk, 0, stream>>>(rbf_v, woutT_v, b_vout, nullptr, out,
                                             nullptr, nullptr, 1024, 1024);
  k_gemm<1><<<dim3(8, 64), blk, 0, stream>>>(rbf_q, woutT_q, b_qout, nullptr, out + 8388608,
                                             nullptr, nullptr, 1024, 1024);
}

// Round 2
// 625.744 us; speedup vs baseline: 1.0770x; 1.0770x over previous
//
#include <hip/hip_runtime.h>
#include <cstdint>

typedef unsigned short u16;
typedef __attribute__((ext_vector_type(8))) short s16x8;   // 8 bf16 (4 VGPRs)
typedef __attribute__((ext_vector_type(4))) float f32x4;

__device__ __forceinline__ u16 f2bf(float f) {
  unsigned int u = __float_as_uint(f);
  unsigned int r = u + 0x7FFFu + ((u >> 16) & 1u);   // RNE
  return (u16)(r >> 16);
}
__device__ __forceinline__ float bf2f(u16 b) {
  return __uint_as_float(((unsigned int)b) << 16);
}
__device__ __forceinline__ f32x4 mfma16(s16x8 a, s16x8 b, f32x4 c) {
  return __builtin_amdgcn_mfma_f32_16x16x32_bf16(a, b, c, 0, 0, 0);
}
__device__ __forceinline__ void gload16(const void* g, void* l) {
  __builtin_amdgcn_global_load_lds((const __attribute__((address_space(1))) void*)g,
                                   (__attribute__((address_space(3))) void*)l, 16, 0, 0);
}

// ---------- transpose + cast: in f32 [K][N] -> out bf16 [N][K] ----------
__global__ __launch_bounds__(256) void k_transpose_cast(const float* __restrict__ in,
                                                        u16* __restrict__ out,
                                                        int K, int N) {
  __shared__ float tile[32][33];
  int n0 = blockIdx.x * 32, k0 = blockIdx.y * 32;
  int tx = threadIdx.x & 31, ty = threadIdx.x >> 5;
#pragma unroll
  for (int i = 0; i < 32; i += 8)
    tile[ty + i][tx] = in[(size_t)(k0 + ty + i) * N + n0 + tx];
  __syncthreads();
#pragma unroll
  for (int i = 0; i < 32; i += 8)
    out[(size_t)(n0 + ty + i) * K + k0 + tx] = f2bf(tile[tx][ty + i]);
}

// ---------- masked mean + relu: grid (B, 4, 2) ----------
__global__ __launch_bounds__(256) void k_mean(const float* __restrict__ v,
                                              const float* __restrict__ q,
                                              const float* __restrict__ vm,
                                              const float* __restrict__ qm,
                                              float* __restrict__ rmean_v,
                                              float* __restrict__ rmean_q) {
  int b = blockIdx.x, dc = blockIdx.y, mod = blockIdx.z;
  const float* x  = mod ? q : v;
  const float* mk = mod ? qm : vm;
  float* out      = mod ? rmean_q : rmean_v;
  int d = dc * 256 + threadIdx.x;
  const float* xb = x + (size_t)b * 256 * 1024 + d;
  const float* mb = mk + b * 256;
  float s = 0.f, ms = 0.f;
  for (int n = 0; n < 256; ++n) {
    float m = mb[n];
    ms += m;
    s = fmaf(xb[(size_t)n * 1024], m, s);
  }
  float mean = s / ms;
  out[b * 1024 + d] = mean > 0.f ? mean : 0.f;
}

// ---------- gate: gs[b][d] = 1 + sigmoid(dot(rmean[b], W[:,d]) + bias[d]) ----------
__global__ __launch_bounds__(256) void k_gate(const float* __restrict__ rmean,
                                              const float* __restrict__ W,
                                              const float* __restrict__ bias,
                                              float* __restrict__ gs) {
  int b = blockIdx.y;
  int d = blockIdx.x * 256 + threadIdx.x;
  const float* r = rmean + b * 1024;
  float acc = bias[d];
#pragma unroll 8
  for (int k = 0; k < 1024; ++k) acc = fmaf(r[k], W[(size_t)k * 1024 + d], acc);
  gs[b * 1024 + d] = 1.f + 1.f / (1.f + expf(-acc));
}

// ---------- relu + bf16 cast: grid (4096,1,2), 8 elems/thread ----------
__global__ __launch_bounds__(256) void k_relucast(const float* __restrict__ v,
                                                  const float* __restrict__ q,
                                                  u16* __restrict__ ov,
                                                  u16* __restrict__ oq) {
  const float* x = blockIdx.z ? q : v;
  u16* o = blockIdx.z ? oq : ov;
  size_t i = (size_t)blockIdx.x * 256 + threadIdx.x;
  const f32x4* xv = (const f32x4*)x;
  f32x4 a = xv[2 * i], b = xv[2 * i + 1];
  s16x8 r;
#pragma unroll
  for (int j = 0; j < 4; ++j) r[j] = (short)f2bf(a[j] > 0.f ? a[j] : 0.f);
#pragma unroll
  for (int j = 0; j < 4; ++j) r[4 + j] = (short)f2bf(b[j] > 0.f ? b[j] : 0.f);
  ((s16x8*)o)[i] = r;
}

// ================= pipelined MFMA GEMM =================
// C[m][n] = A[m][:] . BT[n][:] + bias ; A is stacked v|q (M=16384), half-select
// by m0. Tile 128x256, BK=64, 512 thr (8 waves 2x4), 3-deep LDS ring,
// counted vmcnt(6), phase barriers, setprio, XOR-swizzled LDS (T1..T5).
// EPI 0: bf16 trans out (*mask row, *gs for n<2048); EPI 1: f32 out, ld 1024.
template <int EPI>
__global__ __launch_bounds__(512, 2) void k_mm(const u16* __restrict__ A,
                                               const u16* __restrict__ BTv,
                                               const u16* __restrict__ BTq,
                                               const float* __restrict__ biasv,
                                               const float* __restrict__ biasq,
                                               u16* __restrict__ outv_b,
                                               u16* __restrict__ outq_b,
                                               float* __restrict__ outf,
                                               const float* __restrict__ maskv,
                                               const float* __restrict__ maskq,
                                               const float* __restrict__ gsv,
                                               const float* __restrict__ gsq,
                                               int NBX) {
  __shared__ u16 lA[3][8192];    // 3 x 16KB : A tile 128x64
  __shared__ u16 lB[3][16384];   // 3 x 32KB : B tile 256x64
  int nwg = gridDim.x;
  int cpx = nwg >> 3;                              // nwg % 8 == 0 guaranteed
  int bid = blockIdx.x;
  int id = (bid & 7) * cpx + (bid >> 3);           // XCD-contiguous chunks
  int bx = id % NBX, by = id / NBX;
  int m0 = by * 128, n0 = bx * 256;
  int half = (m0 >= 8192);
  const u16* BT = half ? BTq : BTv;
  const float* bias = half ? biasq : biasv;

  int tid = threadIdx.x;
  int w = tid >> 6, lane = tid & 63;
  int wr = w >> 2, wc = w & 3;
  int la = lane & 15, lb = lane >> 4;

  // staging sources: content at LDS byte o must be global (row(o), col(o)^sw(row))
  const char* srcA[2]; const char* srcB[4];
  int dstAo[2], dstBo[4];
#pragma unroll
  for (int i = 0; i < 2; ++i) {
    int o = i * 8192 + tid * 16;
    int row = o >> 7, colb = o & 127;
    srcA[i] = (const char*)(A + (size_t)(m0 + row) * 1024) + (colb ^ ((row & 7) << 4));
    dstAo[i] = o;
  }
#pragma unroll
  for (int i = 0; i < 4; ++i) {
    int o = i * 8192 + tid * 16;
    int row = o >> 7, colb = o & 127;
    srcB[i] = (const char*)(BT + (size_t)(n0 + row) * 1024) + (colb ^ ((row & 7) << 4));
    dstBo[i] = o;
  }
  auto stageA = [&](int tt, int i) {
    gload16(srcA[i] + tt * 128, (char*)&lA[tt % 3][0] + dstAo[i]);
  };
  auto stageB = [&](int tt, int i) {
    gload16(srcB[i] + tt * 128, (char*)&lB[tt % 3][0] + dstBo[i]);
  };
  auto rdA = [&](int buf, int i, int h) {
    int row = wr * 64 + i * 16 + la;
    int cb = (h * 64 + lb * 16) ^ ((row & 7) << 4);
    return *(const s16x8*)((const char*)&lA[buf][0] + row * 128 + cb);
  };
  auto rdB = [&](int buf, int j, int h) {
    int row = wc * 64 + j * 16 + la;
    int cb = (h * 64 + lb * 16) ^ ((row & 7) << 4);
    return *(const s16x8*)((const char*)&lB[buf][0] + row * 128 + cb);
  };

  f32x4 acc[4][4] = {};

  // prologue: stage tiles 0,1 ; wait own tile-0 loads (6 newest = tile 1)
#pragma unroll
  for (int i = 0; i < 2; ++i) stageA(0, i);
#pragma unroll
  for (int i = 0; i < 4; ++i) stageB(0, i);
#pragma unroll
  for (int i = 0; i < 2; ++i) stageA(1, i);
#pragma unroll
  for (int i = 0; i < 4; ++i) stageB(1, i);
  asm volatile("s_waitcnt vmcnt(6)" ::: "memory");
  __builtin_amdgcn_s_barrier();

  for (int t = 0; t < 16; ++t) {
    int buf = t % 3;
    bool pf = (t + 2 < 16);
    s16x8 af[4], bf_[4];
    // ---- phase 0 : k-half 0 ----
#pragma unroll
    for (int i = 0; i < 4; ++i) af[i] = rdA(buf, i, 0);
#pragma unroll
    for (int j = 0; j < 4; ++j) bf_[j] = rdB(buf, j, 0);
    if (pf) { stageA(t + 2, 0); stageA(t + 2, 1); stageB(t + 2, 0); }
    __builtin_amdgcn_s_barrier();
    asm volatile("s_waitcnt lgkmcnt(0)" ::: "memory");
    __builtin_amdgcn_sched_barrier(0);
    __builtin_amdgcn_s_setprio(1);
#pragma unroll
    for (int i = 0; i < 4; ++i)
#pragma unroll
      for (int j = 0; j < 4; ++j)
        acc[i][j] = mfma16(af[i], bf_[j], acc[i][j]);
    __builtin_amdgcn_s_setprio(0);
    __builtin_amdgcn_s_barrier();
    // ---- phase 1 : k-half 1 ----
#pragma unroll
    for (int i = 0; i < 4; ++i) af[i] = rdA(buf, i, 1);
#pragma unroll
    for (int j = 0; j < 4; ++j) bf_[j] = rdB(buf, j, 1);
    if (pf) { stageB(t + 2, 1); stageB(t + 2, 2); stageB(t + 2, 3); }
    __builtin_amdgcn_s_barrier();
    asm volatile("s_waitcnt lgkmcnt(0)" ::: "memory");
    __builtin_amdgcn_sched_barrier(0);
    __builtin_amdgcn_s_setprio(1);
#pragma unroll
    for (int i = 0; i < 4; ++i)
#pragma unroll
      for (int j = 0; j < 4; ++j)
        acc[i][j] = mfma16(af[i], bf_[j], acc[i][j]);
    __builtin_amdgcn_s_setprio(0);
    // tile boundary: counted wait (never 0 mid-loop); tail drains
    if (pf) asm volatile("s_waitcnt vmcnt(6)" ::: "memory");
    else    asm volatile("s_waitcnt vmcnt(0)" ::: "memory");
    __builtin_amdgcn_s_barrier();
  }

  // epilogue
  u16* outb = half ? outq_b : outv_b;
  const float* mask = half ? maskq : maskv;
  const float* gs = half ? gsq : gsv;
#pragma unroll
  for (int i = 0; i < 4; ++i) {
    int mbase = m0 + wr * 64 + i * 16 + lb * 4;
#pragma unroll
    for (int j = 0; j < 4; ++j) {
      int n = n0 + wc * 64 + j * 16 + la;
      float bn = bias[n];
#pragma unroll
      for (int r = 0; r < 4; ++r) {
        int m = mbase + r;
        float val = acc[i][j][r] + bn;
        if (EPI == 0) {
          int mloc = m & 8191;
          val *= mask[mloc];
          if (n < 2048) val *= gs[((mloc >> 8) << 10) + (n & 1023)];
          outb[(size_t)mloc * 3072 + n] = f2bf(val);
        } else {
          outf[(size_t)m * 1024 + n] = val;
        }
      }
    }
  }
}

// ---------- fused attention per (b, h, 64 q-rows): grid (64, 32) ----------
// K-tile staged to LDS (swizzled-source gload_lds); scores in regs; K region
// reused as P after barrier; V^T scalar-transposed staging (as before).
__global__ __launch_bounds__(256) void k_attn(const u16* __restrict__ trans,
                                              const float* __restrict__ mask,
                                              const float* __restrict__ xorig,
                                              u16* __restrict__ attin) {
  __shared__ u16 Kl[16384];     // 32KB: K [256][64] XOR-swizzled; later P
  __shared__ u16 Vt[64 * 256];  // 32KB: swizzled V^T [d][key]
  int h = blockIdx.x >> 2, qc = blockIdx.x & 3;
  int b = blockIdx.y;
  int t = threadIdx.x, w = t >> 6, lane = t & 63;
  const u16* tb = trans + (size_t)b * 256 * 3072;
  const char* tbc = (const char*)tb;

  // stage K-tile (k part = cols [0,1024), head slice h*64)
#pragma unroll
  for (int i = 0; i < 8; ++i) {
    int o = i * 4096 + t * 16;
    int row = o >> 7, colb = o & 127;
    gload16(tbc + (size_t)row * 6144 + h * 128 + (colb ^ ((row & 7) << 4)),
            (char*)Kl + o);
  }
  // stage V^T (v part = cols [2048, 3072)), XOR-swizzled rows of 512B
#pragma unroll
  for (int i = 0; i < 8; ++i) {
    int c = t + i * 256;
    int key = c >> 3, dc = c & 7;
    s16x8 vv = *(const s16x8*)(tb + (size_t)key * 3072 + 2048 + h * 64 + dc * 8);
    int quad = key >> 3, klow = key & 7;
#pragma unroll
    for (int j = 0; j < 8; ++j) {
      int d = dc * 8 + j;
      Vt[d * 256 + ((quad ^ (d & 7)) << 3) + klow] = (u16)vv[j];
    }
  }
  __syncthreads();

  int la = lane & 15, lb = lane >> 4;
  int q0 = qc * 64 + w * 16;
  const u16* qrow = tb + (size_t)(q0 + la) * 3072 + 1024 + h * 64;  // q part
  s16x8 qf0 = *(const s16x8*)(qrow + lb * 8);
  s16x8 qf1 = *(const s16x8*)(qrow + 32 + lb * 8);

  // QK^T: all scores in registers (16 x f32x4)
  f32x4 sc[16];
#pragma unroll
  for (int nt = 0; nt < 16; ++nt) {
    int row = nt * 16 + la;
    int sw = (row & 7) << 4;
    s16x8 kf0 = *(const s16x8*)((const char*)Kl + row * 128 + ((lb * 16) ^ sw));
    s16x8 kf1 = *(const s16x8*)((const char*)Kl + row * 128 + ((64 + lb * 16) ^ sw));
    f32x4 s = {0.f, 0.f, 0.f, 0.f};
    s = mfma16(qf0, kf0, s);
    s = mfma16(qf1, kf1, s);
    sc[nt] = s;
  }
  __syncthreads();   // all waves done reading Kl before P overwrites it

  u16* Pw = Kl + w * 4096;     // per-wave 8KB P [16 q-rows][256 keys], swizzled
  const float* mb = mask + b * 256;
  float rsum[4] = {0.f, 0.f, 0.f, 0.f};
#pragma unroll
  for (int nt = 0; nt < 16; ++nt) {
    int key = nt * 16 + la;
    float km = mb[key];
    int quad = key >> 3, klow = key & 7;
#pragma unroll
    for (int r = 0; r < 4; ++r) {
      float p = (km != 0.f) ? expf(sc[nt][r] * 0.125f) : 0.f;  // exp(s/sqrt(64))
      u16 pb = f2bf(p);
      int lr = lb * 4 + r;
      rsum[r] += bf2f(pb);
      Pw[lr * 256 + ((quad ^ (lr & 7)) << 3) + klow] = pb;
    }
  }
#pragma unroll
  for (int r = 0; r < 4; ++r) {
    rsum[r] += __shfl_xor(rsum[r], 1);
    rsum[r] += __shfl_xor(rsum[r], 2);
    rsum[r] += __shfl_xor(rsum[r], 4);
    rsum[r] += __shfl_xor(rsum[r], 8);
  }

  f32x4 o[4] = {};
  for (int kt = 0; kt < 8; ++kt) {
    int pq = kt * 4 + lb;
    s16x8 pa = *(const s16x8*)&Pw[la * 256 + ((pq ^ (la & 7)) << 3)];
#pragma unroll
    for (int dt = 0; dt < 4; ++dt) {
      int d = dt * 16 + la;
      s16x8 vb = *(const s16x8*)&Vt[d * 256 + ((pq ^ (d & 7)) << 3)];
      o[dt] = mfma16(pa, vb, o[dt]);
    }
  }

#pragma unroll
  for (int dt = 0; dt < 4; ++dt) {
    int dcol = h * 64 + dt * 16 + la;
#pragma unroll
    for (int r = 0; r < 4; ++r) {
      int qr = q0 + lb * 4 + r;
      size_t gi = ((size_t)b * 256 + qr) * 1024 + dcol;
      attin[gi] = f2bf(xorig[gi] + o[dt][r] / rsum[r]);
    }
  }
}

extern "C" void kernel_launch(void* const* d_in, const int* in_sizes, int n_in,
                              void* d_out, int out_size, void* d_ws, size_t ws_size,
                              hipStream_t stream) {
  const float* v      = (const float*)d_in[0];
  const float* q      = (const float*)d_in[1];
  const float* v_mask = (const float*)d_in[2];
  const float* q_mask = (const float*)d_in[3];
  const float* w_v4q  = (const float*)d_in[4];
  const float* b_v4q  = (const float*)d_in[5];
  const float* w_q4v  = (const float*)d_in[6];
  const float* b_q4v  = (const float*)d_in[7];
  const float* w_vlin = (const float*)d_in[8];
  const float* b_vlin = (const float*)d_in[9];
  const float* w_qlin = (const float*)d_in[10];
  const float* b_qlin = (const float*)d_in[11];
  const float* w_vout = (const float*)d_in[12];
  const float* b_vout = (const float*)d_in[13];
  const float* w_qout = (const float*)d_in[14];
  const float* b_qout = (const float*)d_in[15];
  float* out = (float*)d_out;

  char* ws = (char*)d_ws;
  u16* rbf_v     = (u16*)(ws);                    // 16.8MB, reused as attin_v
  u16* rbf_q     = (u16*)(ws + 16777216);         // 16.8MB (contiguous with rbf_v!)
  u16* trans_v   = (u16*)(ws + 33554432);         // 50.3MB
  u16* wlinT_v   = (u16*)(ws + 83886080);         // 6.3MB
  u16* wlinT_q   = (u16*)(ws + 90177536);         // 6.3MB
  u16* woutT_v   = (u16*)(ws + 96468992);         // 2.1MB
  u16* woutT_q   = (u16*)(ws + 98566144);         // 2.1MB
  float* rmean_v = (float*)(ws + 100663296);
  float* rmean_q = (float*)(ws + 100794368);
  float* gs_v    = (float*)(ws + 100925440);      // 1+q4v_gate (gates v's q/k)
  float* gs_q    = (float*)(ws + 101056512);      // 1+v4q_gate (gates q's q/k)
  u16* trans_q   = (u16*)d_out;                   // parked in d_out; consumed by
                                                  // attn_q before k_mm<1> overwrites

  dim3 blk(256);
  // weights -> bf16 [N][K]
  k_transpose_cast<<<dim3(96, 32), blk, 0, stream>>>(w_vlin, wlinT_v, 1024, 3072);
  k_transpose_cast<<<dim3(96, 32), blk, 0, stream>>>(w_qlin, wlinT_q, 1024, 3072);
  k_transpose_cast<<<dim3(32, 32), blk, 0, stream>>>(w_vout, woutT_v, 1024, 1024);
  k_transpose_cast<<<dim3(32, 32), blk, 0, stream>>>(w_qout, woutT_q, 1024, 1024);
  // masked means (relu'd)
  k_mean<<<dim3(32, 4, 2), blk, 0, stream>>>(v, q, v_mask, q_mask, rmean_v, rmean_q);
  // gates (cross-wired: v-attention gated by q-mean and vice versa)
  k_gate<<<dim3(4, 32), blk, 0, stream>>>(rmean_q, w_q4v, b_q4v, gs_v);
  k_gate<<<dim3(4, 32), blk, 0, stream>>>(rmean_v, w_v4q, b_v4q, gs_q);
  // relu + cast (stacked bf16 A matrix, M=16384)
  k_relucast<<<dim3(4096, 1, 2), blk, 0, stream>>>(v, q, rbf_v, rbf_q);
  // trans = (relu(x) @ Wlin + b) * mask, k/q thirds * (1+gate) — fused v|q
  k_mm<0><<<dim3(1536), dim3(512), 0, stream>>>(rbf_v, wlinT_v, wlinT_q,
                                                b_vlin, b_qlin, trans_v, trans_q,
                                                nullptr, v_mask, q_mask, gs_v, gs_q, 12);
  // attention; writes bf16(x + update) into rbf (attin)
  k_attn<<<dim3(64, 32), blk, 0, stream>>>(trans_v, v_mask, v, rbf_v);
  k_attn<<<dim3(64, 32), blk, 0, stream>>>(trans_q, q_mask, q, rbf_q);
  // out = attin @ Wout + b — fused v|q, f32 out (concat order matches d_out)
  k_mm<1><<<dim3(512), dim3(512), 0, stream>>>(rbf_v, woutT_v, woutT_q,
                                               b_vout, b_qout, nullptr, nullptr,
                                               out, nullptr, nullptr, nullptr, nullptr, 4);
}

// Round 4
// 546.297 us; speedup vs baseline: 1.2336x; 1.1454x over previous
//
#include <hip/hip_runtime.h>
#include <cstdint>

typedef unsigned short u16;
typedef __attribute__((ext_vector_type(8))) short s16x8;   // 8 bf16 (4 VGPRs)
typedef __attribute__((ext_vector_type(4))) float f32x4;

__device__ __forceinline__ u16 f2bf(float f) {
  unsigned int u = __float_as_uint(f);
  return (u16)((u + 0x7FFFu + ((u >> 16) & 1u)) >> 16);   // RNE
}
__device__ __forceinline__ float bf2f(u16 b) {
  return __uint_as_float(((unsigned int)b) << 16);
}
__device__ __forceinline__ f32x4 mfma16(s16x8 a, s16x8 b, f32x4 c) {
  return __builtin_amdgcn_mfma_f32_16x16x32_bf16(a, b, c, 0, 0, 0);
}
__device__ __forceinline__ void gload16(const void* g, void* l) {
  __builtin_amdgcn_global_load_lds((const __attribute__((address_space(1))) void*)g,
                                   (__attribute__((address_space(3))) void*)l, 16, 0, 0);
}

// ---------- weight transpose+cast pair: f32 [K][N] -> bf16 [N][K], z selects ----------
__global__ __launch_bounds__(256) void k_wt(const float* __restrict__ in0, u16* __restrict__ out0,
                                            const float* __restrict__ in1, u16* __restrict__ out1,
                                            int K, int N) {
  const float* in = blockIdx.z ? in1 : in0;
  u16* out = blockIdx.z ? out1 : out0;
  __shared__ float tile[32][33];
  int n0 = blockIdx.x * 32, k0 = blockIdx.y * 32;
  int tx = threadIdx.x & 31, ty = threadIdx.x >> 5;
#pragma unroll
  for (int i = 0; i < 32; i += 8)
    tile[ty + i][tx] = in[(size_t)(k0 + ty + i) * N + n0 + tx];
  __syncthreads();
#pragma unroll
  for (int i = 0; i < 32; i += 8)
    out[(size_t)(n0 + ty + i) * K + k0 + tx] = f2bf(tile[tx][ty + i]);
}

// ---------- fused relu-cast + masked-sum: grid (32b, 8=dc*2+mod, 8 nsplit) ----------
__global__ __launch_bounds__(256) void k_prep(const float* __restrict__ v,
                                              const float* __restrict__ q,
                                              const float* __restrict__ vm,
                                              const float* __restrict__ qm,
                                              u16* __restrict__ rbf,
                                              float* __restrict__ raw,
                                              float* __restrict__ msum) {
  int b = blockIdx.x;
  int mod = blockIdx.y & 1, dc = blockIdx.y >> 1;
  int ns = blockIdx.z;
  const float* x = mod ? q : v;
  const float* mk = (mod ? qm : vm) + b * 256;
  int d = dc * 256 + threadIdx.x;
  const float* xb = x + ((size_t)b * 256 + ns * 32) * 1024 + d;
  u16* ob = rbf + ((size_t)(mod * 8192 + b * 256 + ns * 32)) * 1024 + d;
  float s = 0.f;
#pragma unroll 4
  for (int n = 0; n < 32; ++n) {
    float xv = xb[(size_t)n * 1024];
    s = fmaf(xv, mk[ns * 32 + n], s);
    ob[(size_t)n * 1024] = f2bf(xv > 0.f ? xv : 0.f);
  }
  atomicAdd(&raw[(mod * 32 + b) * 1024 + d], s);
  if (threadIdx.x == 0 && dc == 0) {
    float t = 0.f;
    for (int n = 0; n < 32; ++n) t += mk[ns * 32 + n];
    atomicAdd(&msum[mod * 32 + b], t);
  }
}

// ---------- gates: gs = 1 + sigmoid(relu(mean) @ W + b), grid (4, 32, 2) ----------
__global__ __launch_bounds__(256) void k_gate(const float* __restrict__ raw,
                                              const float* __restrict__ msum,
                                              const float* __restrict__ Wq4v,
                                              const float* __restrict__ bq4v,
                                              const float* __restrict__ Wv4q,
                                              const float* __restrict__ bv4q,
                                              float* __restrict__ gsv,
                                              float* __restrict__ gsq) {
  int b = blockIdx.y, z = blockIdx.z;
  int srcmod = z == 0 ? 1 : 0;   // gs_v <- q-mean, gs_q <- v-mean (cross-wired)
  const float* W = z == 0 ? Wq4v : Wv4q;
  const float* bias = z == 0 ? bq4v : bv4q;
  float* gs = z == 0 ? gsv : gsq;
  const float* r = raw + (srcmod * 32 + b) * 1024;
  float inv = 1.f / msum[srcmod * 32 + b];
  int d = blockIdx.x * 256 + threadIdx.x;
  float acc = bias[d];
#pragma unroll 8
  for (int k = 0; k < 1024; ++k) {
    float m = r[k] * inv;
    m = m > 0.f ? m : 0.f;
    acc = fmaf(m, W[(size_t)k * 1024 + d], acc);
  }
  gs[b * 1024 + d] = 1.f + 1.f / (1.f + expf(-acc));
}

// ================= 256x256 MFMA GEMM, BK=32 ring-4, counted vmcnt =================
// A stacked v|q [16384][1024] bf16; BT per-half [N][1024]. 512 thr = 8 waves (2x4),
// per-wave C = 128x64 (acc[8][4]). LDS 128KB: 4 half-K slots x (A 16KB + B 16KB).
// Per half-tile: 2 phases x {ds_read || 2 gload_lds || bar || lgkmcnt(0) || prio ||
// 16 MFMA || bar}, vmcnt(4) once per half-tile (drain only last 2).
// EPI 0: bf16 trans out (*mask row, *gs n<2048). EPI 1: f32 out ld=1024.
template <int EPI>
__global__ __launch_bounds__(512, 2) void k_mm(const u16* __restrict__ A,
                                               const u16* __restrict__ BTv,
                                               const u16* __restrict__ BTq,
                                               const float* __restrict__ biasv,
                                               const float* __restrict__ biasq,
                                               u16* __restrict__ outv_b,
                                               u16* __restrict__ outq_b,
                                               float* __restrict__ outf,
                                               const float* __restrict__ maskv,
                                               const float* __restrict__ maskq,
                                               const float* __restrict__ gsv,
                                               const float* __restrict__ gsq) {
  __shared__ u16 lA[4][8192];    // 4 x 16KB : A half-tile 256 rows x 32 (64B rows)
  __shared__ u16 lB[4][8192];
  constexpr int NU = 32;         // K=1024 / 32
  int nwg = gridDim.x, cpx = nwg >> 3, bid = blockIdx.x;
  int id = (bid & 7) * cpx + (bid >> 3);     // XCD-contiguous chunks
  int by = id & 63, bx = id >> 6;            // column-major: by fastest (B L2-resident)
  int m0 = by * 256, n0 = bx * 256;
  int half = (m0 >= 8192);
  const u16* BT = half ? BTq : BTv;

  int tid = threadIdx.x, w = tid >> 6, lane = tid & 63;
  int wr = w >> 2, wc = w & 3;
  int la = lane & 15, lb = lane >> 4;

  // staging: LDS byte o holds global (row(o), col(o) ^ sw(row)); sw = (row&3)<<4
  const char* srcA[2]; const char* srcB[2]; int dstO[2];
#pragma unroll
  for (int s = 0; s < 2; ++s) {
    int o = s * 8192 + tid * 16;
    int row = o >> 6, colb = o & 63;
    int sw = (row & 3) << 4;
    srcA[s] = (const char*)A + (size_t)(m0 + row) * 2048 + (colb ^ sw);
    srcB[s] = (const char*)BT + (size_t)(n0 + row) * 2048 + (colb ^ sw);
    dstO[s] = o;
  }
  int aoffs[8], boffs[4];
#pragma unroll
  for (int i = 0; i < 8; ++i) {
    int r = wr * 128 + i * 16 + la;
    aoffs[i] = r * 64 + ((lb * 16) ^ ((r & 3) << 4));
  }
#pragma unroll
  for (int j = 0; j < 4; ++j) {
    int r = wc * 64 + j * 16 + la;
    boffs[j] = r * 64 + ((lb * 16) ^ ((r & 3) << 4));
  }

  f32x4 acc[8][4] = {};

  // prologue: stage half-tiles 0 and 1 ; wait tile-0 (4 newest = tile 1)
#pragma unroll
  for (int s = 0; s < 2; ++s) gload16(srcA[s], (char*)&lA[0][0] + dstO[s]);
#pragma unroll
  for (int s = 0; s < 2; ++s) gload16(srcB[s], (char*)&lB[0][0] + dstO[s]);
#pragma unroll
  for (int s = 0; s < 2; ++s) gload16(srcA[s] + 64, (char*)&lA[1][0] + dstO[s]);
#pragma unroll
  for (int s = 0; s < 2; ++s) gload16(srcB[s] + 64, (char*)&lB[1][0] + dstO[s]);
  asm volatile("s_waitcnt vmcnt(4)" ::: "memory");
  __builtin_amdgcn_s_barrier();

  for (int u = 0; u < NU; ++u) {
    const char* cA = (const char*)&lA[u & 3][0];
    const char* cB = (const char*)&lB[u & 3][0];
    int pu = u + 2;
    char* wA = (char*)&lA[pu & 3][0];
    char* wB = (char*)&lB[pu & 3][0];
    bool pf = pu < NU;
    s16x8 a0[4], b0[4];
    // ---- phase 0 : M-half 0 ----
#pragma unroll
    for (int j = 0; j < 4; ++j) b0[j] = *(const s16x8*)(cB + boffs[j]);
#pragma unroll
    for (int i = 0; i < 4; ++i) a0[i] = *(const s16x8*)(cA + aoffs[i]);
    if (pf) {
      gload16(srcA[0] + pu * 64, wA + dstO[0]);
      gload16(srcA[1] + pu * 64, wA + dstO[1]);
    }
    __builtin_amdgcn_s_barrier();
    asm volatile("s_waitcnt lgkmcnt(0)" ::: "memory");
    __builtin_amdgcn_sched_barrier(0);
    __builtin_amdgcn_s_setprio(1);
#pragma unroll
    for (int i = 0; i < 4; ++i)
#pragma unroll
      for (int j = 0; j < 4; ++j)
        acc[i][j] = mfma16(a0[i], b0[j], acc[i][j]);
    __builtin_amdgcn_s_setprio(0);
    __builtin_amdgcn_s_barrier();
    // ---- phase 1 : M-half 1 (B frags reused in regs) ----
    s16x8 a1[4];
#pragma unroll
    for (int i = 0; i < 4; ++i) a1[i] = *(const s16x8*)(cA + aoffs[4 + i]);
    if (pf) {
      gload16(srcB[0] + pu * 64, wB + dstO[0]);
      gload16(srcB[1] + pu * 64, wB + dstO[1]);
    }
    __builtin_amdgcn_s_barrier();
    asm volatile("s_waitcnt lgkmcnt(0)" ::: "memory");
    __builtin_amdgcn_sched_barrier(0);
    __builtin_amdgcn_s_setprio(1);
#pragma unroll
    for (int i = 0; i < 4; ++i)
#pragma unroll
      for (int j = 0; j < 4; ++j)
        acc[4 + i][j] = mfma16(a1[i], b0[j], acc[4 + i][j]);
    __builtin_amdgcn_s_setprio(0);
    if (u < NU - 2) asm volatile("s_waitcnt vmcnt(4)" ::: "memory");
    else            asm volatile("s_waitcnt vmcnt(0)" ::: "memory");
    __builtin_amdgcn_s_barrier();
  }

  // epilogue
  const float* bias = half ? biasq : biasv;
  const float* mask = half ? maskq : maskv;
  const float* gs = half ? gsq : gsv;
#pragma unroll
  for (int i = 0; i < 8; ++i) {
    int mbase = m0 + wr * 128 + i * 16 + lb * 4;
#pragma unroll
    for (int j = 0; j < 4; ++j) {
      int n = n0 + wc * 64 + j * 16 + la;
      float bn = bias[n];
#pragma unroll
      for (int r = 0; r < 4; ++r) {
        int m = mbase + r;
        float val = acc[i][j][r] + bn;
        if (EPI == 0) {
          int mloc = m & 8191;
          val *= mask[mloc];
          if (n < 2048) val *= gs[((mloc >> 8) << 10) + (n & 1023)];
          (half ? outq_b : outv_b)[(size_t)mloc * 3072 + n] = f2bf(val);
        } else {
          outf[(size_t)m * 1024 + n] = val;
        }
      }
    }
  }
}

// ---------- v-third transpose: trans[b][key][2048+d] -> vT[b][d][key] (bf16) ----------
// grid (4 keytile, 16 dtile, 64 = mod*32+b), 64x64 tiles, swizzled LDS.
__global__ __launch_bounds__(256) void k_vtrans(const u16* __restrict__ tr0,
                                                const u16* __restrict__ tr1,
                                                u16* __restrict__ vt0,
                                                u16* __restrict__ vt1) {
  int bz = blockIdx.z;
  int mod = bz >> 5, b = bz & 31;
  const u16* tr = mod ? tr1 : tr0;
  u16* vt = mod ? vt1 : vt0;
  __shared__ u16 tile[64 * 64];   // phys col-oct = key-oct ^ (d>>3)
  int kt = blockIdx.x, dt = blockIdx.y;
  int t = threadIdx.x, tx = t & 7, ty = t >> 3;   // ty 0..31
  const u16* src = tr + (size_t)b * 786432 + 2048 + dt * 64;
#pragma unroll
  for (int i = 0; i < 2; ++i) {
    int key = ty + i * 32;
    s16x8 vv = *(const s16x8*)(src + (size_t)(kt * 64 + key) * 3072 + tx * 8);
    int oct = key >> 3;
#pragma unroll
    for (int j = 0; j < 8; ++j) {
      int d = tx * 8 + j;
      tile[d * 64 + ((oct ^ (d >> 3)) << 3) + (key & 7)] = (u16)vv[j];
    }
  }
  __syncthreads();
  u16* dst = vt + (size_t)b * 262144 + (size_t)dt * 64 * 256 + kt * 64;
#pragma unroll
  for (int i = 0; i < 2; ++i) {
    int d = ty + i * 32;
    s16x8 ov = *(const s16x8*)&tile[d * 64 + ((tx ^ (d >> 3)) << 3)];
    *(s16x8*)(dst + (size_t)d * 256 + tx * 8) = ov;
  }
}

// ---------- fused attention, grid (64 = h*4+qc, 32 b, 2 mod) ----------
__global__ __launch_bounds__(256) void k_attn(const u16* __restrict__ tr0,
                                              const u16* __restrict__ tr1,
                                              const u16* __restrict__ vt0,
                                              const u16* __restrict__ vt1,
                                              const float* __restrict__ mk0,
                                              const float* __restrict__ mk1,
                                              const float* __restrict__ x0,
                                              const float* __restrict__ x1,
                                              u16* __restrict__ ao0,
                                              u16* __restrict__ ao1) {
  int z = blockIdx.z;
  const u16* trans = z ? tr1 : tr0;
  const u16* vt = z ? vt1 : vt0;
  const float* mask = z ? mk1 : mk0;
  const float* xorig = z ? x1 : x0;
  u16* attin = z ? ao1 : ao0;

  __shared__ u16 Kl[16384];     // 32KB: K [256][64] XOR-swizzled; reused as P
  __shared__ u16 Vt[64 * 256];  // 32KB: V^T [d][key], key-oct ^ (d&7) swizzle
  int h = blockIdx.x >> 2, qc = blockIdx.x & 3;
  int b = blockIdx.y;
  int t = threadIdx.x, w = t >> 6, lane = t & 63;
  const u16* tb = trans + (size_t)b * 256 * 3072;
  const char* tbc = (const char*)tb;

  // stage K (k-third cols [0,1024), head slice), 16B-XOR swizzle on 128B rows
#pragma unroll
  for (int i = 0; i < 8; ++i) {
    int o = i * 4096 + t * 16;
    int row = o >> 7, colb = o & 127;
    gload16(tbc + (size_t)row * 6144 + h * 128 + (colb ^ ((row & 7) << 4)),
            (char*)Kl + o);
  }
  // stage V^T from pre-transposed vT, key-oct swizzle
  const char* vtb = (const char*)(vt + (size_t)b * 262144 + (size_t)h * 64 * 256);
#pragma unroll
  for (int i = 0; i < 8; ++i) {
    int o = i * 4096 + t * 16;
    int d = o >> 9, oct = (o >> 4) & 31;
    gload16(vtb + d * 512 + ((oct ^ (d & 7)) << 4), (char*)Vt + o);
  }
  __syncthreads();

  int la = lane & 15, lb = lane >> 4;
  int q0 = qc * 64 + w * 16;
  const u16* qrow = tb + (size_t)(q0 + la) * 3072 + 1024 + h * 64;  // q-third
  s16x8 qf0 = *(const s16x8*)(qrow + lb * 8);
  s16x8 qf1 = *(const s16x8*)(qrow + 32 + lb * 8);

  // QK^T, scores in regs
  f32x4 sc[16];
#pragma unroll
  for (int nt = 0; nt < 16; ++nt) {
    int row = nt * 16 + la;
    int sw = (row & 7) << 4;
    s16x8 kf0 = *(const s16x8*)((const char*)Kl + row * 128 + ((lb * 16) ^ sw));
    s16x8 kf1 = *(const s16x8*)((const char*)Kl + row * 128 + ((64 + lb * 16) ^ sw));
    f32x4 s = {0.f, 0.f, 0.f, 0.f};
    s = mfma16(qf0, kf0, s);
    s = mfma16(qf1, kf1, s);
    sc[nt] = s;
  }
  __syncthreads();   // all waves done with Kl before P overwrites

  u16* Pw = Kl + w * 4096;     // per-wave P [16][256], swizzled
  const float* mb = mask + b * 256;
  float rsum[4] = {0.f, 0.f, 0.f, 0.f};
#pragma unroll
  for (int nt = 0; nt < 16; ++nt) {
    int key = nt * 16 + la;
    float km = mb[key];
    int quad = key >> 3, klow = key & 7;
#pragma unroll
    for (int r = 0; r < 4; ++r) {
      float p = (km != 0.f) ? expf(sc[nt][r] * 0.125f) : 0.f;  // exp(s/sqrt(64))
      u16 pb = f2bf(p);
      int lr = lb * 4 + r;
      rsum[r] += bf2f(pb);
      Pw[lr * 256 + ((quad ^ (lr & 7)) << 3) + klow] = pb;
    }
  }
#pragma unroll
  for (int r = 0; r < 4; ++r) {
    rsum[r] += __shfl_xor(rsum[r], 1);
    rsum[r] += __shfl_xor(rsum[r], 2);
    rsum[r] += __shfl_xor(rsum[r], 4);
    rsum[r] += __shfl_xor(rsum[r], 8);
  }
  __syncthreads();

  f32x4 o[4] = {};
  for (int kt = 0; kt < 8; ++kt) {
    int pq = kt * 4 + lb;
    s16x8 pa = *(const s16x8*)&Pw[la * 256 + ((pq ^ (la & 7)) << 3)];
#pragma unroll
    for (int dt = 0; dt < 4; ++dt) {
      int d = dt * 16 + la;
      s16x8 vb = *(const s16x8*)&Vt[d * 256 + ((pq ^ (d & 7)) << 3)];
      o[dt] = mfma16(pa, vb, o[dt]);
    }
  }

#pragma unroll
  for (int dt = 0; dt < 4; ++dt) {
    int dcol = h * 64 + dt * 16 + la;
#pragma unroll
    for (int r = 0; r < 4; ++r) {
      int qr = q0 + lb * 4 + r;
      size_t gi = ((size_t)b * 256 + qr) * 1024 + dcol;
      attin[gi] = f2bf(xorig[gi] + o[dt][r] / rsum[r]);
    }
  }
}

extern "C" void kernel_launch(void* const* d_in, const int* in_sizes, int n_in,
                              void* d_out, int out_size, void* d_ws, size_t ws_size,
                              hipStream_t stream) {
  const float* v      = (const float*)d_in[0];
  const float* q      = (const float*)d_in[1];
  const float* v_mask = (const float*)d_in[2];
  const float* q_mask = (const float*)d_in[3];
  const float* w_v4q  = (const float*)d_in[4];
  const float* b_v4q  = (const float*)d_in[5];
  const float* w_q4v  = (const float*)d_in[6];
  const float* b_q4v  = (const float*)d_in[7];
  const float* w_vlin = (const float*)d_in[8];
  const float* b_vlin = (const float*)d_in[9];
  const float* w_qlin = (const float*)d_in[10];
  const float* b_qlin = (const float*)d_in[11];
  const float* w_vout = (const float*)d_in[12];
  const float* b_vout = (const float*)d_in[13];
  const float* w_qout = (const float*)d_in[14];
  const float* b_qout = (const float*)d_in[15];
  float* out = (float*)d_out;

  char* ws = (char*)d_ws;
  u16* rbf       = (u16*)(ws);                    // 33.5MB stacked v|q; becomes attin
  u16* rbf_v     = rbf;
  u16* rbf_q     = (u16*)(ws + 16777216);
  u16* woutT_v   = (u16*)(ws + 33554432);         // 2.1MB
  u16* woutT_q   = (u16*)(ws + 35651584);         // 2.1MB
  u16* trans_v   = (u16*)(ws + 37748736);         // 50.3MB
  // overlay region (wlinT/raw/gs dead after k_mm<0>; vT_v reuses it)
  u16* wlinT_v   = (u16*)(ws + 88080384);         // 6.3MB
  u16* wlinT_q   = (u16*)(ws + 94371840);         // 6.3MB
  float* raw     = (float*)(ws + 100663296);      // 2x32x1024 f32 sums
  float* msum    = (float*)(ws + 100925440);      // 2x32 f32
  float* gs_v    = (float*)(ws + 100925696);      // 1+q4v_gate
  float* gs_q    = (float*)(ws + 101056768);      // 1+v4q_gate
  u16* vT_v      = (u16*)(ws + 88080384);         // 16.8MB overlay (after mm0)
  u16* trans_q   = (u16*)d_out;                   // 50.3MB parked in d_out
  u16* vT_q      = (u16*)((char*)d_out + 50331648);  // 16.8MB (total exactly 64MiB)

  dim3 blk(256);
  hipMemsetAsync(raw, 0, 262400, stream);         // raw + msum
  // weights -> bf16 [N][K]
  k_wt<<<dim3(96, 32, 2), blk, 0, stream>>>(w_vlin, wlinT_v, w_qlin, wlinT_q, 1024, 3072);
  k_wt<<<dim3(32, 32, 2), blk, 0, stream>>>(w_vout, woutT_v, w_qout, woutT_q, 1024, 1024);
  // fused relu-cast + masked partial sums
  k_prep<<<dim3(32, 8, 8), blk, 0, stream>>>(v, q, v_mask, q_mask, rbf, raw, msum);
  // gates (cross-wired)
  k_gate<<<dim3(4, 32, 2), blk, 0, stream>>>(raw, msum, w_q4v, b_q4v, w_v4q, b_v4q, gs_v, gs_q);
  // trans = (relu(x) @ Wlin + b) * mask, k/q thirds * (1+gate) — fused v|q
  k_mm<0><<<dim3(768), dim3(512), 0, stream>>>(rbf, wlinT_v, wlinT_q, b_vlin, b_qlin,
                                               trans_v, trans_q, nullptr,
                                               v_mask, q_mask, gs_v, gs_q);
  // v-third -> vT[b][d][key]
  k_vtrans<<<dim3(4, 16, 64), blk, 0, stream>>>(trans_v, trans_q, vT_v, vT_q);
  // attention (both modalities); writes bf16(x + update) into rbf
  k_attn<<<dim3(64, 32, 2), blk, 0, stream>>>(trans_v, trans_q, vT_v, vT_q,
                                              v_mask, q_mask, v, q, rbf_v, rbf_q);
  // out = attin @ Wout + b — f32, overwrites d_out after attn consumed it
  k_mm<1><<<dim3(256), dim3(512), 0, stream>>>(rbf, woutT_v, woutT_q, b_vout, b_qout,
                                               nullptr, nullptr, out,
                                               nullptr, nullptr, nullptr, nullptr);
}

// Round 5
// 536.758 us; speedup vs baseline: 1.2556x; 1.0178x over previous
//
#include <hip/hip_runtime.h>
#include <cstdint>

typedef unsigned short u16;
typedef __attribute__((ext_vector_type(8))) short s16x8;   // 8 bf16 (4 VGPRs)
typedef __attribute__((ext_vector_type(4))) float f32x4;

__device__ __forceinline__ u16 f2bf(float f) {
  unsigned int u = __float_as_uint(f);
  return (u16)((u + 0x7FFFu + ((u >> 16) & 1u)) >> 16);   // RNE
}
__device__ __forceinline__ float bf2f(u16 b) {
  return __uint_as_float(((unsigned int)b) << 16);
}
__device__ __forceinline__ f32x4 mfma16(s16x8 a, s16x8 b, f32x4 c) {
  return __builtin_amdgcn_mfma_f32_16x16x32_bf16(a, b, c, 0, 0, 0);
}
__device__ __forceinline__ void gload16(const void* g, void* l) {
  __builtin_amdgcn_global_load_lds((const __attribute__((address_space(1))) void*)g,
                                   (__attribute__((address_space(3))) void*)l, 16, 0, 0);
}

// ---------- weight transpose+cast pair: f32 [K][N] -> bf16 [N][K], z selects ----------
__global__ __launch_bounds__(256) void k_wt(const float* __restrict__ in0, u16* __restrict__ out0,
                                            const float* __restrict__ in1, u16* __restrict__ out1,
                                            int K, int N) {
  const float* in = blockIdx.z ? in1 : in0;
  u16* out = blockIdx.z ? out1 : out0;
  __shared__ float tile[32][33];
  int n0 = blockIdx.x * 32, k0 = blockIdx.y * 32;
  int tx = threadIdx.x & 31, ty = threadIdx.x >> 5;
#pragma unroll
  for (int i = 0; i < 32; i += 8)
    tile[ty + i][tx] = in[(size_t)(k0 + ty + i) * N + n0 + tx];
  __syncthreads();
#pragma unroll
  for (int i = 0; i < 32; i += 8)
    out[(size_t)(n0 + ty + i) * K + k0 + tx] = f2bf(tile[tx][ty + i]);
}

// ---------- fused relu-cast + masked-sum: grid (32b, 8=dc*2+mod, 8 nsplit) ----------
__global__ __launch_bounds__(256) void k_prep(const float* __restrict__ v,
                                              const float* __restrict__ q,
                                              const float* __restrict__ vm,
                                              const float* __restrict__ qm,
                                              u16* __restrict__ rbf,
                                              float* __restrict__ raw,
                                              float* __restrict__ msum) {
  int b = blockIdx.x;
  int mod = blockIdx.y & 1, dc = blockIdx.y >> 1;
  int ns = blockIdx.z;
  const float* x = mod ? q : v;
  const float* mk = (mod ? qm : vm) + b * 256;
  int d = dc * 256 + threadIdx.x;
  const float* xb = x + ((size_t)b * 256 + ns * 32) * 1024 + d;
  u16* ob = rbf + ((size_t)(mod * 8192 + b * 256 + ns * 32)) * 1024 + d;
  float s = 0.f;
#pragma unroll 4
  for (int n = 0; n < 32; ++n) {
    float xv = xb[(size_t)n * 1024];
    s = fmaf(xv, mk[ns * 32 + n], s);
    ob[(size_t)n * 1024] = f2bf(xv > 0.f ? xv : 0.f);
  }
  atomicAdd(&raw[(mod * 32 + b) * 1024 + d], s);
  if (threadIdx.x == 0 && dc == 0) {
    float t = 0.f;
    for (int n = 0; n < 32; ++n) t += mk[ns * 32 + n];
    atomicAdd(&msum[mod * 32 + b], t);
  }
}

// ---------- gates: gs = 1 + sigmoid(relu(mean) @ W + b), grid (4, 32, 2) ----------
__global__ __launch_bounds__(256) void k_gate(const float* __restrict__ raw,
                                              const float* __restrict__ msum,
                                              const float* __restrict__ Wq4v,
                                              const float* __restrict__ bq4v,
                                              const float* __restrict__ Wv4q,
                                              const float* __restrict__ bv4q,
                                              float* __restrict__ gsv,
                                              float* __restrict__ gsq) {
  int b = blockIdx.y, z = blockIdx.z;
  int srcmod = z == 0 ? 1 : 0;   // gs_v <- q-mean, gs_q <- v-mean (cross-wired)
  const float* W = z == 0 ? Wq4v : Wv4q;
  const float* bias = z == 0 ? bq4v : bv4q;
  float* gs = z == 0 ? gsv : gsq;
  const float* r = raw + (srcmod * 32 + b) * 1024;
  float inv = 1.f / msum[srcmod * 32 + b];
  int d = blockIdx.x * 256 + threadIdx.x;
  float acc = bias[d];
#pragma unroll 8
  for (int k = 0; k < 1024; ++k) {
    float m = r[k] * inv;
    m = m > 0.f ? m : 0.f;
    acc = fmaf(m, W[(size_t)k * 1024 + d], acc);
  }
  gs[b * 1024 + d] = 1.f + 1.f / (1.f + expf(-acc));
}

// ================= 256x256 MFMA GEMM, 8-phase schedule (T2+T3+T4+T5) =================
// A stacked v|q [16384][1024] bf16; BT per-half [N][1024]. 512 thr = 8 waves (2x4),
// per-wave C = 128x64 (acc[8][4]). LDS 128KB = {A,B} x 4 slots (dbuf x khalf),
// slot = [256 rows][32 k] 64B rows, XOR swizzle c ^= ((row>>1)&3)<<4 (8 bank regions).
// Per K-tile(64): 4 phases = (jhalf x khalf) quadrants, 16 MFMA each.
// One half-tile staged per phase (2 gloads); vmcnt(6) only at P4/P8 (=3 half-tiles
// in flight); each vmcnt proves the NEXT 4 phases' operands landed. Slot staged at
// phase p was last read at phase p-1 (one barrier upstream) -> race-free.
template <int EPI>
__global__ __launch_bounds__(512, 2) void k_mm(const u16* __restrict__ A,
                                               const u16* __restrict__ BTv,
                                               const u16* __restrict__ BTq,
                                               const float* __restrict__ biasv,
                                               const float* __restrict__ biasq,
                                               u16* __restrict__ outv_b,
                                               u16* __restrict__ outq_b,
                                               float* __restrict__ outf,
                                               const float* __restrict__ maskv,
                                               const float* __restrict__ maskq,
                                               const float* __restrict__ gsv,
                                               const float* __restrict__ gsq) {
  __shared__ u16 lA[4][8192];   // slot = (ktile&1)*2 + khalf
  __shared__ u16 lB[4][8192];
  int nwg = gridDim.x, cpx = nwg >> 3, bid = blockIdx.x;
  int id = (bid & 7) * cpx + (bid >> 3);     // XCD-contiguous chunks
  int by = id & 63, bx = id >> 6;            // column-major: by fastest (B L2-resident)
  int m0 = by * 256, n0 = bx * 256;
  int half = (m0 >= 8192);
  const u16* BT = half ? BTq : BTv;

  int tid = threadIdx.x, w = tid >> 6, lane = tid & 63;
  int wr = w >> 2, wc = w & 3;
  int la = lane & 15, lb = lane >> 4;

  // staging sources for the 2 per-thread loads (LDS bytes o0, o1 of a 16KB slot)
  int o0 = tid * 16, o1 = 8192 + tid * 16;
  int r0 = o0 >> 6, c0 = o0 & 63;
  int r1 = o1 >> 6, c1 = o1 & 63;
  const char* sA0 = (const char*)A + (size_t)(m0 + r0) * 2048 + (c0 ^ (((r0 >> 1) & 3) << 4));
  const char* sA1 = (const char*)A + (size_t)(m0 + r1) * 2048 + (c1 ^ (((r1 >> 1) & 3) << 4));
  const char* sB0 = (const char*)BT + (size_t)(n0 + r0) * 2048 + (c0 ^ (((r0 >> 1) & 3) << 4));
  const char* sB1 = (const char*)BT + (size_t)(n0 + r1) * 2048 + (c1 ^ (((r1 >> 1) & 3) << 4));

  auto stA = [&](int slot, int kt, int kh) {
    int go = kt * 128 + kh * 64;
    gload16(sA0 + go, (char*)&lA[slot][0] + o0);
    gload16(sA1 + go, (char*)&lA[slot][0] + o1);
  };
  auto stB = [&](int slot, int kt, int kh) {
    int go = kt * 128 + kh * 64;
    gload16(sB0 + go, (char*)&lB[slot][0] + o0);
    gload16(sB1 + go, (char*)&lB[slot][0] + o1);
  };

  int aoffs[8], boffs[4];
#pragma unroll
  for (int i = 0; i < 8; ++i) {
    int r = wr * 128 + i * 16 + la;
    aoffs[i] = r * 64 + ((lb * 16) ^ (((r >> 1) & 3) << 4));
  }
#pragma unroll
  for (int j = 0; j < 4; ++j) {
    int r = wc * 64 + j * 16 + la;
    boffs[j] = r * 64 + ((lb * 16) ^ (((r >> 1) & 3) << 4));
  }

  f32x4 acc[8][4] = {};
  s16x8 a[8], b[2];

  auto rdA8 = [&](int slot) {
#pragma unroll
    for (int i = 0; i < 8; ++i)
      a[i] = *(const s16x8*)((const char*)&lA[slot][0] + aoffs[i]);
  };
  auto rdB2 = [&](int slot, int jh) {
    b[0] = *(const s16x8*)((const char*)&lB[slot][0] + boffs[jh * 2]);
    b[1] = *(const s16x8*)((const char*)&lB[slot][0] + boffs[jh * 2 + 1]);
  };
  auto gate = [&]() {
    __builtin_amdgcn_s_barrier();
    asm volatile("s_waitcnt lgkmcnt(0)" ::: "memory");
    __builtin_amdgcn_sched_barrier(0);
    __builtin_amdgcn_s_setprio(1);
  };
  auto mfJ0 = [&]() {
#pragma unroll
    for (int i = 0; i < 8; ++i) {
      acc[i][0] = mfma16(a[i], b[0], acc[i][0]);
      acc[i][1] = mfma16(a[i], b[1], acc[i][1]);
    }
  };
  auto mfJ1 = [&]() {
#pragma unroll
    for (int i = 0; i < 8; ++i) {
      acc[i][2] = mfma16(a[i], b[0], acc[i][2]);
      acc[i][3] = mfma16(a[i], b[1], acc[i][3]);
    }
  };
  auto close = [&]() {
    __builtin_amdgcn_s_setprio(0);
    __builtin_amdgcn_s_barrier();
  };

  // prologue: K0 all 4 half-tiles + K1 first 3, consumption order; leave 3 in flight
  stA(0, 0, 0); stB(0, 0, 0); stA(1, 0, 1); stB(1, 0, 1);
  stA(2, 1, 0); stB(2, 1, 0); stA(3, 1, 1);
  asm volatile("s_waitcnt vmcnt(6)" ::: "memory");
  __builtin_amdgcn_s_barrier();

#pragma unroll 1
  for (int it = 0; it < 8; ++it) {
    int k1t = 2 * it + 1, nx = 2 * it + 2, nx2 = 2 * it + 3;
    bool pf = it < 7;
    // P1: cur0 (jh0,k0); stage cur1's last half (B dbuf1 k1)
    rdA8(0); rdB2(0, 0);
    stB(3, k1t, 1);
    gate(); mfJ0(); close();
    // P2: cur0 (jh1,k0); stage next-even A k0 (slot free after P1)
    rdB2(0, 1);
    if (pf) stA(0, nx, 0);
    gate(); mfJ1(); close();
    // P3: cur0 (jh0,k1); stage next-even B k0
    rdA8(1); rdB2(1, 0);
    if (pf) stB(0, nx, 0);
    gate(); mfJ0(); close();
    // P4: cur0 (jh1,k1); stage next-even A k1; counted vmcnt
    rdB2(1, 1);
    if (pf) stA(1, nx, 1);
    gate(); mfJ1();
    __builtin_amdgcn_s_setprio(0);
    if (pf) asm volatile("s_waitcnt vmcnt(6)" ::: "memory");
    else    asm volatile("s_waitcnt vmcnt(0)" ::: "memory");
    __builtin_amdgcn_s_barrier();
    // P5: cur1 (jh0,k0); stage next-even B k1
    rdA8(2); rdB2(2, 0);
    if (pf) stB(1, nx, 1);
    gate(); mfJ0(); close();
    // P6: cur1 (jh1,k0); stage next-odd A k0
    rdB2(2, 1);
    if (pf) stA(2, nx2, 0);
    gate(); mfJ1(); close();
    // P7: cur1 (jh0,k1); stage next-odd B k0
    rdA8(3); rdB2(3, 0);
    if (pf) stB(2, nx2, 0);
    gate(); mfJ0(); close();
    // P8: cur1 (jh1,k1); stage next-odd A k1; counted vmcnt
    rdB2(3, 1);
    if (pf) stA(3, nx2, 1);
    gate(); mfJ1();
    __builtin_amdgcn_s_setprio(0);
    if (pf) asm volatile("s_waitcnt vmcnt(6)" ::: "memory");
    else    asm volatile("s_waitcnt vmcnt(0)" ::: "memory");
    __builtin_amdgcn_s_barrier();
  }

  // epilogue
  const float* bias = half ? biasq : biasv;
  const float* mask = half ? maskq : maskv;
  const float* gs = half ? gsq : gsv;
#pragma unroll
  for (int i = 0; i < 8; ++i) {
    int mbase = m0 + wr * 128 + i * 16 + lb * 4;
#pragma unroll
    for (int j = 0; j < 4; ++j) {
      int n = n0 + wc * 64 + j * 16 + la;
      float bn = bias[n];
#pragma unroll
      for (int r = 0; r < 4; ++r) {
        int m = mbase + r;
        float val = acc[i][j][r] + bn;
        if (EPI == 0) {
          int mloc = m & 8191;
          val *= mask[mloc];
          if (n < 2048) val *= gs[((mloc >> 8) << 10) + (n & 1023)];
          (half ? outq_b : outv_b)[(size_t)mloc * 3072 + n] = f2bf(val);
        } else {
          outf[(size_t)m * 1024 + n] = val;
        }
      }
    }
  }
}

// ---------- v-third transpose: trans[b][key][2048+d] -> vT[b][d][key] (bf16) ----------
// grid (4 keytile, 16 dtile, 64 = mod*32+b), 64x64 tiles, swizzled LDS.
__global__ __launch_bounds__(256) void k_vtrans(const u16* __restrict__ tr0,
                                                const u16* __restrict__ tr1,
                                                u16* __restrict__ vt0,
                                                u16* __restrict__ vt1) {
  int bz = blockIdx.z;
  int mod = bz >> 5, b = bz & 31;
  const u16* tr = mod ? tr1 : tr0;
  u16* vt = mod ? vt1 : vt0;
  __shared__ u16 tile[64 * 64];   // phys col-oct = key-oct ^ (d>>3)
  int kt = blockIdx.x, dt = blockIdx.y;
  int t = threadIdx.x, tx = t & 7, ty = t >> 3;   // ty 0..31
  const u16* src = tr + (size_t)b * 786432 + 2048 + dt * 64;
#pragma unroll
  for (int i = 0; i < 2; ++i) {
    int key = ty + i * 32;
    s16x8 vv = *(const s16x8*)(src + (size_t)(kt * 64 + key) * 3072 + tx * 8);
    int oct = key >> 3;
#pragma unroll
    for (int j = 0; j < 8; ++j) {
      int d = tx * 8 + j;
      tile[d * 64 + ((oct ^ (d >> 3)) << 3) + (key & 7)] = (u16)vv[j];
    }
  }
  __syncthreads();
  u16* dst = vt + (size_t)b * 262144 + (size_t)dt * 64 * 256 + kt * 64;
#pragma unroll
  for (int i = 0; i < 2; ++i) {
    int d = ty + i * 32;
    s16x8 ov = *(const s16x8*)&tile[d * 64 + ((tx ^ (d >> 3)) << 3)];
    *(s16x8*)(dst + (size_t)d * 256 + tx * 8) = ov;
  }
}

// ---------- fused attention, grid (64 = h*4+qc, 32 b, 2 mod) ----------
__global__ __launch_bounds__(256) void k_attn(const u16* __restrict__ tr0,
                                              const u16* __restrict__ tr1,
                                              const u16* __restrict__ vt0,
                                              const u16* __restrict__ vt1,
                                              const float* __restrict__ mk0,
                                              const float* __restrict__ mk1,
                                              const float* __restrict__ x0,
                                              const float* __restrict__ x1,
                                              u16* __restrict__ ao0,
                                              u16* __restrict__ ao1) {
  int z = blockIdx.z;
  const u16* trans = z ? tr1 : tr0;
  const u16* vt = z ? vt1 : vt0;
  const float* mask = z ? mk1 : mk0;
  const float* xorig = z ? x1 : x0;
  u16* attin = z ? ao1 : ao0;

  __shared__ u16 Kl[16384];     // 32KB: K [256][64] XOR-swizzled; reused as P
  __shared__ u16 Vt[64 * 256];  // 32KB: V^T [d][key], key-oct ^ (d&7) swizzle
  int h = blockIdx.x >> 2, qc = blockIdx.x & 3;
  int b = blockIdx.y;
  int t = threadIdx.x, w = t >> 6, lane = t & 63;
  const u16* tb = trans + (size_t)b * 256 * 3072;
  const char* tbc = (const char*)tb;

  // stage K (k-third cols [0,1024), head slice), 16B-XOR swizzle on 128B rows
#pragma unroll
  for (int i = 0; i < 8; ++i) {
    int o = i * 4096 + t * 16;
    int row = o >> 7, colb = o & 127;
    gload16(tbc + (size_t)row * 6144 + h * 128 + (colb ^ ((row & 7) << 4)),
            (char*)Kl + o);
  }
  // stage V^T from pre-transposed vT, key-oct swizzle
  const char* vtb = (const char*)(vt + (size_t)b * 262144 + (size_t)h * 64 * 256);
#pragma unroll
  for (int i = 0; i < 8; ++i) {
    int o = i * 4096 + t * 16;
    int d = o >> 9, oct = (o >> 4) & 31;
    gload16(vtb + d * 512 + ((oct ^ (d & 7)) << 4), (char*)Vt + o);
  }
  __syncthreads();

  int la = lane & 15, lb = lane >> 4;
  int q0 = qc * 64 + w * 16;
  const u16* qrow = tb + (size_t)(q0 + la) * 3072 + 1024 + h * 64;  // q-third
  s16x8 qf0 = *(const s16x8*)(qrow + lb * 8);
  s16x8 qf1 = *(const s16x8*)(qrow + 32 + lb * 8);

  // QK^T, scores in regs
  f32x4 sc[16];
#pragma unroll
  for (int nt = 0; nt < 16; ++nt) {
    int row = nt * 16 + la;
    int sw = (row & 7) << 4;
    s16x8 kf0 = *(const s16x8*)((const char*)Kl + row * 128 + ((lb * 16) ^ sw));
    s16x8 kf1 = *(const s16x8*)((const char*)Kl + row * 128 + ((64 + lb * 16) ^ sw));
    f32x4 s = {0.f, 0.f, 0.f, 0.f};
    s = mfma16(qf0, kf0, s);
    s = mfma16(qf1, kf1, s);
    sc[nt] = s;
  }
  __syncthreads();   // all waves done with Kl before P overwrites

  u16* Pw = Kl + w * 4096;     // per-wave P [16][256], swizzled
  const float* mb = mask + b * 256;
  float rsum[4] = {0.f, 0.f, 0.f, 0.f};
#pragma unroll
  for (int nt = 0; nt < 16; ++nt) {
    int key = nt * 16 + la;
    float km = mb[key];
    int quad = key >> 3, klow = key & 7;
#pragma unroll
    for (int r = 0; r < 4; ++r) {
      float p = (km != 0.f) ? expf(sc[nt][r] * 0.125f) : 0.f;  // exp(s/sqrt(64))
      u16 pb = f2bf(p);
      int lr = lb * 4 + r;
      rsum[r] += bf2f(pb);
      Pw[lr * 256 + ((quad ^ (lr & 7)) << 3) + klow] = pb;
    }
  }
#pragma unroll
  for (int r = 0; r < 4; ++r) {
    rsum[r] += __shfl_xor(rsum[r], 1);
    rsum[r] += __shfl_xor(rsum[r], 2);
    rsum[r] += __shfl_xor(rsum[r], 4);
    rsum[r] += __shfl_xor(rsum[r], 8);
  }
  __syncthreads();

  f32x4 o[4] = {};
  for (int kt = 0; kt < 8; ++kt) {
    int pq = kt * 4 + lb;
    s16x8 pa = *(const s16x8*)&Pw[la * 256 + ((pq ^ (la & 7)) << 3)];
#pragma unroll
    for (int dt = 0; dt < 4; ++dt) {
      int d = dt * 16 + la;
      s16x8 vb = *(const s16x8*)&Vt[d * 256 + ((pq ^ (d & 7)) << 3)];
      o[dt] = mfma16(pa, vb, o[dt]);
    }
  }

#pragma unroll
  for (int dt = 0; dt < 4; ++dt) {
    int dcol = h * 64 + dt * 16 + la;
#pragma unroll
    for (int r = 0; r < 4; ++r) {
      int qr = q0 + lb * 4 + r;
      size_t gi = ((size_t)b * 256 + qr) * 1024 + dcol;
      attin[gi] = f2bf(xorig[gi] + o[dt][r] / rsum[r]);
    }
  }
}

extern "C" void kernel_launch(void* const* d_in, const int* in_sizes, int n_in,
                              void* d_out, int out_size, void* d_ws, size_t ws_size,
                              hipStream_t stream) {
  const float* v      = (const float*)d_in[0];
  const float* q      = (const float*)d_in[1];
  const float* v_mask = (const float*)d_in[2];
  const float* q_mask = (const float*)d_in[3];
  const float* w_v4q  = (const float*)d_in[4];
  const float* b_v4q  = (const float*)d_in[5];
  const float* w_q4v  = (const float*)d_in[6];
  const float* b_q4v  = (const float*)d_in[7];
  const float* w_vlin = (const float*)d_in[8];
  const float* b_vlin = (const float*)d_in[9];
  const float* w_qlin = (const float*)d_in[10];
  const float* b_qlin = (const float*)d_in[11];
  const float* w_vout = (const float*)d_in[12];
  const float* b_vout = (const float*)d_in[13];
  const float* w_qout = (const float*)d_in[14];
  const float* b_qout = (const float*)d_in[15];
  float* out = (float*)d_out;

  char* ws = (char*)d_ws;
  u16* rbf       = (u16*)(ws);                    // 33.5MB stacked v|q; becomes attin
  u16* rbf_v     = rbf;
  u16* rbf_q     = (u16*)(ws + 16777216);
  u16* woutT_v   = (u16*)(ws + 33554432);         // 2.1MB
  u16* woutT_q   = (u16*)(ws + 35651584);         // 2.1MB
  u16* trans_v   = (u16*)(ws + 37748736);         // 50.3MB
  // overlay region (wlinT/raw/gs dead after k_mm<0>; vT_v reuses it)
  u16* wlinT_v   = (u16*)(ws + 88080384);         // 6.3MB
  u16* wlinT_q   = (u16*)(ws + 94371840);         // 6.3MB
  float* raw     = (float*)(ws + 100663296);      // 2x32x1024 f32 sums
  float* msum    = (float*)(ws + 100925440);      // 2x32 f32
  float* gs_v    = (float*)(ws + 100925696);      // 1+q4v_gate
  float* gs_q    = (float*)(ws + 101056768);      // 1+v4q_gate
  u16* vT_v      = (u16*)(ws + 88080384);         // 16.8MB overlay (after mm0)
  u16* trans_q   = (u16*)d_out;                   // 50.3MB parked in d_out
  u16* vT_q      = (u16*)((char*)d_out + 50331648);  // 16.8MB (total exactly 64MiB)

  dim3 blk(256);
  hipMemsetAsync(raw, 0, 262400, stream);         // raw + msum
  // weights -> bf16 [N][K]
  k_wt<<<dim3(96, 32, 2), blk, 0, stream>>>(w_vlin, wlinT_v, w_qlin, wlinT_q, 1024, 3072);
  k_wt<<<dim3(32, 32, 2), blk, 0, stream>>>(w_vout, woutT_v, w_qout, woutT_q, 1024, 1024);
  // fused relu-cast + masked partial sums
  k_prep<<<dim3(32, 8, 8), blk, 0, stream>>>(v, q, v_mask, q_mask, rbf, raw, msum);
  // gates (cross-wired)
  k_gate<<<dim3(4, 32, 2), blk, 0, stream>>>(raw, msum, w_q4v, b_q4v, w_v4q, b_v4q, gs_v, gs_q);
  // trans = (relu(x) @ Wlin + b) * mask, k/q thirds * (1+gate) — fused v|q
  k_mm<0><<<dim3(768), dim3(512), 0, stream>>>(rbf, wlinT_v, wlinT_q, b_vlin, b_qlin,
                                               trans_v, trans_q, nullptr,
                                               v_mask, q_mask, gs_v, gs_q);
  // v-third -> vT[b][d][key]
  k_vtrans<<<dim3(4, 16, 64), blk, 0, stream>>>(trans_v, trans_q, vT_v, vT_q);
  // attention (both modalities); writes bf16(x + update) into rbf
  k_attn<<<dim3(64, 32, 2), blk, 0, stream>>>(trans_v, trans_q, vT_v, vT_q,
                                              v_mask, q_mask, v, q, rbf_v, rbf_q);
  // out = attin @ Wout + b — f32, overwrites d_out after attn consumed it
  k_mm<1><<<dim3(256), dim3(512), 0, stream>>>(rbf, woutT_v, woutT_q, b_vout, b_qout,
                                               nullptr, nullptr, out,
                                               nullptr, nullptr, nullptr, nullptr);
}